// Round 2
// baseline (601.946 us; speedup 1.0000x reference)
//
#include <hip/hip_runtime.h>
#include <hip/hip_bf16.h>
#include <math.h>

// Problem constants (from reference)
#define NEXP 8
#define DIM_D 1024
#define DIM_H 4096
#define NB 4096

typedef __attribute__((ext_vector_type(8))) short short8;
typedef __attribute__((ext_vector_type(4))) float floatx4;

__device__ __forceinline__ unsigned short f2bf(float x) {
  __hip_bfloat16 h = __float2bfloat16(x);   // RNE
  unsigned short u;
  __builtin_memcpy(&u, &h, 2);
  return u;
}
__device__ __forceinline__ unsigned int pack2bf(float a, float b) {
  return (unsigned int)f2bf(a) | ((unsigned int)f2bf(b) << 16);
}

// async global->LDS, 16B per lane; LDS dest = wave-uniform base + lane*16
__device__ __forceinline__ void async_copy16(const void* g, void* l) {
  __builtin_amdgcn_global_load_lds(
      (const __attribute__((address_space(1))) unsigned int*)g,
      (__attribute__((address_space(3))) unsigned int*)l, 16, 0, 0);
}

// ---------------- setup: bucket rows by expert (f32 t, bit-exact vs ref) ----
__global__ void setup_kernel(const float* __restrict__ t,
                             int* __restrict__ offs, int* __restrict__ perm) {
  __shared__ int cnt[NEXP];
  __shared__ int cur[NEXP];
  const int tid = threadIdx.x;
  if (tid < NEXP) cnt[tid] = 0;
  __syncthreads();
  for (int i = tid; i < NB; i += 256) {
    int e = (int)(t[i] * 8.0f);             // t/H_STEP, pow2 -> exact
    e = e < 0 ? 0 : (e > NEXP - 1 ? NEXP - 1 : e);
    atomicAdd(&cnt[e], 1);
  }
  __syncthreads();
  if (tid == 0) {
    int s = 0;
    for (int e = 0; e < NEXP; ++e) { offs[e] = s; cur[e] = s; s += cnt[e]; }
    offs[NEXP] = s;
  }
  __syncthreads();
  for (int i = tid; i < NB; i += 256) {
    int e = (int)(t[i] * 8.0f);
    e = e < 0 ? 0 : (e > NEXP - 1 ? NEXP - 1 : e);
    int slot = atomicAdd(&cur[e], 1);
    perm[slot] = i;
  }
}

// ---------------- f32 -> bf16 bulk convert (for y) ----------------
__global__ __launch_bounds__(256)
void cvt_kernel(const float* __restrict__ in, __hip_bfloat16* __restrict__ out) {
  const long long i = ((long long)blockIdx.x * 256 + threadIdx.x) * 8;
  const float4 a = *(const float4*)(in + i);
  const float4 b = *(const float4*)(in + i + 4);
  unsigned int r[4];
  r[0] = pack2bf(a.x, a.y);
  r[1] = pack2bf(a.z, a.w);
  r[2] = pack2bf(b.x, b.y);
  r[3] = pack2bf(b.z, b.w);
  *(uint4*)(out + i) = *(const uint4*)r;
}

// ------- f32 transpose + bf16 convert: in [R][C] f32 -> out [C][R] bf16 ----
// 64x64 tile as a pure u32-word transpose: each u32 packs an in-row PAIR
// (rows 2m, 2m+1) at one column -> exactly one out-row u32 word.
// LDS [32 pairs][69] u32; stride 69 (== 5 mod 32): both sides 2-way-max banks.
__global__ __launch_bounds__(256)
void transpose_cvt_kernel(const float* __restrict__ in,
                          __hip_bfloat16* __restrict__ out, int R, int C) {
  __shared__ unsigned int wbuf[32 * 69];
  const long long base = (long long)blockIdx.z * R * C;
  const int c0 = blockIdx.x * 64;
  const int r0 = blockIdx.y * 64;
  const int t = threadIdx.x;
  {
    const int p = t >> 3, g = t & 7;      // row-pair p, 8-col group g
    const float* s0 = in + base + (long long)(r0 + 2 * p) * C + c0 + g * 8;
    const float4 a0 = *(const float4*)(s0);
    const float4 a1 = *(const float4*)(s0 + 4);
    const float4 b0 = *(const float4*)(s0 + C);
    const float4 b1v = *(const float4*)(s0 + C + 4);
    unsigned int* dp = &wbuf[p * 69 + g * 8];
    dp[0] = pack2bf(a0.x, b0.x);
    dp[1] = pack2bf(a0.y, b0.y);
    dp[2] = pack2bf(a0.z, b0.z);
    dp[3] = pack2bf(a0.w, b0.w);
    dp[4] = pack2bf(a1.x, b1v.x);
    dp[5] = pack2bf(a1.y, b1v.y);
    dp[6] = pack2bf(a1.z, b1v.z);
    dp[7] = pack2bf(a1.w, b1v.w);
  }
  __syncthreads();
  {
    const int oc = t >> 2, rq = t & 3;    // out row c0+oc, word group rq
    __align__(16) unsigned int res[8];
#pragma unroll
    for (int j = 0; j < 8; ++j) res[j] = wbuf[(rq * 8 + j) * 69 + oc];
    __hip_bfloat16* dstp = out + base + (long long)(c0 + oc) * R + r0 + rq * 16;
    *(uint4*)dstp = *(const uint4*)&res[0];
    *(uint4*)(dstp + 8) = *(const uint4*)&res[4];
  }
}

// ---------------- grouped NT GEMM, 4-buffer deep-pipelined ----------------
// C[m][n] = sum_k A[m][k] * BT[n][k]; 128x128 tile, BK=64.
// LDS: 4 buffers x (A 16KB | B 16KB) = 128KB. Prefetch 3 K-tiles deep with
// COUNTED vmcnt (16 steady / 8 / 0 tail) + raw s_barrier -> loads stay in
// flight across barriers (T3+T4), removing the vmcnt(0) drain stall.
// LDS layout per tile: byte = row*128 + (kc ^ (row&7))*16 (kc = 16B chunk of
// the 64-elem K-row). XOR swizzle applied to BOTH the pre-permuted global
// source of global_load_lds (dest linear) and the ds_read address ->
// conflict-free ds_read_b128 (any 8 consecutive lanes hit 8 distinct slots).
// XCD-aware remap: lin%8 (=XCD) owns one expert -> A-panel L2-resident.
// 4 waves (2x2), each 64x64 output = acc[4][4] of 16x16x32 MFMA.
// MODE 0: A = y_bf16 (rows via perm), epilogue tanh(x+b1) -> hid bf16 (permuted)
// MODE 1: A = hid (contiguous rows), epilogue full output -> f32 out[perm[i]]
template <int MODE>
__global__ __launch_bounds__(256, 1)
void gemm_kernel(const __hip_bfloat16* __restrict__ A,
                 const __hip_bfloat16* __restrict__ BT,   // [E][N][K] bf16
                 const float* __restrict__ bias,          // [E][N] f32
                 const int* __restrict__ offs, const int* __restrict__ perm,
                 void* __restrict__ dstv,                 // MODE0: bf16*, MODE1: f32*
                 const float* __restrict__ yin,           // [B][N] f32 (MODE 1)
                 const float* __restrict__ scales,        // [N] f32 (MODE 1)
                 const float* __restrict__ shifta,
                 const float* __restrict__ shiftb,
                 int K, int N) {
  // XCD remap: gridDim.y==256 (=8 experts x 32 mt), gridDim.x = N/128 (pow2).
  // Default dispatch round-robins lin%8 across XCDs; give XCD c expert c.
  const int lin = blockIdx.x + gridDim.x * blockIdx.y;
  const int xcd = lin & 7;
  const int idx = lin >> 3;
  const int gx = gridDim.x;
  const int shift = (gx == 8) ? 3 : 5;      // log2(gridDim.x); 8 or 32 here
  const int bx = idx & (gx - 1);
  const int by = xcd * (gridDim.y >> 3) + (idx >> shift);

  const int e  = by >> 5;
  const int mt = by & 31;
  const int off = offs[e];
  const int cnt = offs[e + 1] - off;
  const int m0 = mt * 128;
  if (m0 >= cnt) return;                    // early-exit for padded grid
  const int rows = min(128, cnt - m0);
  const int n0 = bx * 128;

  __shared__ __align__(16) char lds[131072];  // 4 x (A 16K | B 16K)
  __shared__ int rowmap[128];

  const int tid = threadIdx.x;
  if (tid < 128) {
    int r = tid < rows ? tid : rows - 1;    // clamp: stage valid memory
    rowmap[tid] = (MODE == 0) ? perm[off + m0 + r] : (off + m0 + r);
  }
  __syncthreads();

  const int w = tid >> 6, l = tid & 63;

  // ---- staging: linear chunk c = j*256+tid at byte 16c; c -> row=c>>3,
  // slot s=c&7 holds data kc = s ^ (row&7)  (source pre-swizzle).
  const int srow = tid >> 3;                // row within 32-row j-block
  const int kc = (tid & 7) ^ (srow & 7);
  const __hip_bfloat16* aptr[4];
  const __hip_bfloat16* bptr[4];
#pragma unroll
  for (int j = 0; j < 4; ++j) {
    const int row = j * 32 + srow;
    aptr[j] = A + (long long)rowmap[row] * K + kc * 8;
    bptr[j] = BT + ((long long)e * N + n0 + row) * K + kc * 8;
  }

  auto stage = [&](int buf) {               // 8 VMEM ops per call
    char* dst = lds + (buf << 15);
#pragma unroll
    for (int j = 0; j < 4; ++j) {
      async_copy16(aptr[j], dst + j * 4096 + w * 1024);
      async_copy16(bptr[j], dst + 16384 + j * 4096 + w * 1024);
      aptr[j] += 64; bptr[j] += 64;
    }
  };

  floatx4 acc[4][4];
#pragma unroll
  for (int i = 0; i < 4; ++i)
#pragma unroll
    for (int j = 0; j < 4; ++j) acc[i][j] = (floatx4){0.f, 0.f, 0.f, 0.f};

  const int wm = w >> 1, wn = w & 1;
  const int fr = l & 15;                    // M (A) / N (B) index in fragment
  const int fq = l >> 4;                    // K 16B-sub-chunk in fragment
  const int fx = fr & 7;
  int aoff[2], boff[2];
#pragma unroll
  for (int ks = 0; ks < 2; ++ks) {
    aoff[ks] = (wm * 64 + fr) * 128 + (((ks * 4) | fq) ^ fx) * 16;
    boff[ks] = 16384 + (wn * 64 + fr) * 128 + (((ks * 4) | fq) ^ fx) * 16;
  }

  auto compute = [&](int buf) {
    const char* src = lds + (buf << 15);
#pragma unroll
    for (int ks = 0; ks < 2; ++ks) {
      short8 af[4], bf[4];
#pragma unroll
      for (int mi = 0; mi < 4; ++mi)
        af[mi] = *(const short8*)(src + mi * 2048 + aoff[ks]);
#pragma unroll
      for (int ni = 0; ni < 4; ++ni)
        bf[ni] = *(const short8*)(src + ni * 2048 + boff[ks]);
#pragma unroll
      for (int mi = 0; mi < 4; ++mi)
#pragma unroll
        for (int ni = 0; ni < 4; ++ni)
          acc[mi][ni] = __builtin_amdgcn_mfma_f32_16x16x32_bf16(
              af[mi], bf[ni], acc[mi][ni], 0, 0, 0);
    }
  };

  const int nt = K >> 6;                    // K-tiles of 64 (>=3 always here)

  stage(0); stage(1); stage(2);             // 24 outstanding

  // Per iter: wait own stage(t) landed (counted!), barrier (=> whole tile t
  // landed), prefetch t+3 (its buffer was freed by LAST iter's end barrier),
  // compute t, end barrier (frees buf t&3 for stage(t+4)).
#define K_ITER(T, WAITN)                                          \
  do {                                                            \
    asm volatile("s_waitcnt vmcnt(" #WAITN ")" ::: "memory");     \
    __builtin_amdgcn_s_barrier();                                 \
    __builtin_amdgcn_sched_barrier(0);                            \
    if ((T) + 3 < nt) stage(((T) + 3) & 3);                       \
    compute((T) & 3);                                             \
    __builtin_amdgcn_sched_barrier(0);                            \
    __builtin_amdgcn_s_barrier();                                 \
  } while (0)

  int t = 0;
  for (; t < nt - 2; ++t) K_ITER(t, 16);
  K_ITER(t, 8);  ++t;
  K_ITER(t, 0);
#undef K_ITER

  float av = 0.f, bv = 0.f;
  if (MODE == 1) {
    const float sa = 1.f / (1.f + expf(-shifta[0]));
    const float sb = 1.f / (1.f + expf(-shiftb[0]));
    av = 0.0f + sa * (-1.0f - 0.0f);         // EIGINIT + sig*(EIGMIN-EIGINIT)
    bv = 0.0f + sb * (1.0f - 0.0f);          // EIGINIT + sig*(EIGMAX-EIGINIT)
  }

  // C/D layout: col = lane&15, row = (lane>>4)*4 + reg
#pragma unroll
  for (int mi = 0; mi < 4; ++mi) {
#pragma unroll
    for (int r = 0; r < 4; ++r) {
      const int rl = wm * 64 + mi * 16 + fq * 4 + r;
      if (rl >= rows) continue;
      const int i = off + m0 + rl;
      const int orig = (MODE == 1) ? perm[i] : 0;
#pragma unroll
      for (int ni = 0; ni < 4; ++ni) {
        const int cg = n0 + wn * 64 + ni * 16 + fr;
        const float x = acc[mi][ni][r] + bias[e * N + cg];
        if (MODE == 0) {
          ((__hip_bfloat16*)dstv)[(long long)i * N + cg] = __float2bfloat16(tanhf(x));
        } else {
          const float sc = 1.f / (1.f + expf(-scales[cg]));
          const float yv = yin[(long long)orig * N + cg];
          const float res = 0.5f * ((bv - av) * sc * x + (av + bv) * yv);
          ((float*)dstv)[(long long)orig * N + cg] = res;   // f32 output!
        }
      }
    }
  }
}

extern "C" void kernel_launch(void* const* d_in, const int* in_sizes, int n_in,
                              void* d_out, int out_size, void* d_ws, size_t ws_size,
                              hipStream_t stream) {
  const float* t      = (const float*)d_in[0];
  const float* y      = (const float*)d_in[1];
  const float* W1     = (const float*)d_in[2];
  const float* b1     = (const float*)d_in[3];
  const float* W2     = (const float*)d_in[4];
  const float* b2     = (const float*)d_in[5];
  const float* scales = (const float*)d_in[6];
  const float* shifta = (const float*)d_in[7];
  const float* shiftb = (const float*)d_in[8];

  // ws layout: [0,64MB)   transposed bf16 weights (W1T, then reused for W2T)
  //            [64,96MB)  hid bf16 [NB][DIM_H], permuted row order
  //            [96,104MB) y_bf16 [NB][DIM_D]
  //            [104MB,..) offs[16] + perm[NB]
  char* ws = (char*)d_ws;
  __hip_bfloat16* WT  = (__hip_bfloat16*)ws;
  __hip_bfloat16* hid = (__hip_bfloat16*)(ws + (size_t)64 * 1024 * 1024);
  __hip_bfloat16* ybf = (__hip_bfloat16*)(ws + (size_t)96 * 1024 * 1024);
  int* offs = (int*)(ws + (size_t)104 * 1024 * 1024);
  int* perm = offs + 16;

  setup_kernel<<<1, 256, 0, stream>>>(t, offs, perm);

  cvt_kernel<<<(NB * DIM_D) / (256 * 8), 256, 0, stream>>>(y, ybf);

  // W1 [E][D][DH] f32 -> WT [E][DH][D] bf16
  transpose_cvt_kernel<<<dim3(DIM_H / 64, DIM_D / 64, NEXP), 256, 0, stream>>>(
      W1, WT, DIM_D, DIM_H);
  // hid = tanh(y @ W1 + b1), grouped by expert
  gemm_kernel<0><<<dim3(DIM_H / 128, NEXP * 32), 256, 0, stream>>>(
      ybf, WT, b1, offs, perm, hid, nullptr, nullptr, nullptr, nullptr,
      DIM_D, DIM_H);
  // W2 [E][DH][D] f32 -> WT [E][D][DH] bf16 (safe reuse: stream-ordered)
  transpose_cvt_kernel<<<dim3(DIM_D / 64, DIM_H / 64, NEXP), 256, 0, stream>>>(
      W2, WT, DIM_H, DIM_D);
  // out = 0.5*((b-a)*sig(scales)*(hid@W2+b2) + (a+b)*y), scattered via perm
  gemm_kernel<1><<<dim3(DIM_D / 128, NEXP * 32), 256, 0, stream>>>(
      hid, WT, b2, offs, perm, d_out, y, scales, shifta, shiftb,
      DIM_H, DIM_D);
}

// Round 3
// 505.309 us; speedup vs baseline: 1.1912x; 1.1912x over previous
//
#include <hip/hip_runtime.h>
#include <hip/hip_bf16.h>
#include <math.h>

// Problem constants (from reference)
#define NEXP 8
#define DIM_D 1024
#define DIM_H 4096
#define NB 4096

typedef __attribute__((ext_vector_type(8))) short short8;
typedef __attribute__((ext_vector_type(4))) float floatx4;

__device__ __forceinline__ unsigned short f2bf(float x) {
  __hip_bfloat16 h = __float2bfloat16(x);   // RNE
  unsigned short u;
  __builtin_memcpy(&u, &h, 2);
  return u;
}
__device__ __forceinline__ unsigned int pack2bf(float a, float b) {
  return (unsigned int)f2bf(a) | ((unsigned int)f2bf(b) << 16);
}

// async global->LDS, 16B per lane; LDS dest = wave-uniform base + lane*16
__device__ __forceinline__ void async_copy16(const void* g, void* l) {
  __builtin_amdgcn_global_load_lds(
      (const __attribute__((address_space(1))) unsigned int*)g,
      (__attribute__((address_space(3))) unsigned int*)l, 16, 0, 0);
}

// ---------------- setup: bucket rows by expert + build work-list ----------
// wl[64]: entry (mt<<4)|e at slot r*8+e  -> block lin%8 == e%8 == XCD affinity
__global__ void setup_kernel(const float* __restrict__ t,
                             int* __restrict__ offs, int* __restrict__ perm,
                             int* __restrict__ wl) {
  __shared__ int cnt[NEXP];
  __shared__ int cur[NEXP];
  const int tid = threadIdx.x;
  if (tid < NEXP) cnt[tid] = 0;
  __syncthreads();
  for (int i = tid; i < NB; i += 256) {
    int e = (int)(t[i] * 8.0f);             // t/H_STEP, pow2 -> exact
    e = e < 0 ? 0 : (e > NEXP - 1 ? NEXP - 1 : e);
    atomicAdd(&cnt[e], 1);
  }
  __syncthreads();
  if (tid == 0) {
    int s = 0;
    for (int e = 0; e < NEXP; ++e) { offs[e] = s; cur[e] = s; s += cnt[e]; }
    offs[NEXP] = s;
    for (int i = 0; i < 64; ++i) wl[i] = -1;
    for (int e = 0; e < NEXP; ++e) {        // column e = expert e (XCD e)
      int tiles = (cnt[e] + 127) >> 7;
      int lim = tiles < 8 ? tiles : 8;
      for (int r = 0; r < lim; ++r) wl[r * 8 + e] = (r << 4) | e;
    }
    int free_s = 0;                         // overflow (pathological skew)
    for (int e = 0; e < NEXP; ++e) {
      int tiles = (cnt[e] + 127) >> 7;
      for (int r = 8; r < tiles; ++r) {
        while (free_s < 64 && wl[free_s] >= 0) ++free_s;
        if (free_s < 64) wl[free_s] = (r << 4) | e;
      }
    }
  }
  __syncthreads();
  for (int i = tid; i < NB; i += 256) {
    int e = (int)(t[i] * 8.0f);
    e = e < 0 ? 0 : (e > NEXP - 1 ? NEXP - 1 : e);
    int slot = atomicAdd(&cur[e], 1);
    perm[slot] = i;
  }
}

// ---------------- f32 -> bf16 bulk convert (for y) ----------------
__global__ __launch_bounds__(256)
void cvt_kernel(const float* __restrict__ in, __hip_bfloat16* __restrict__ out) {
  const long long i = ((long long)blockIdx.x * 256 + threadIdx.x) * 8;
  const float4 a = *(const float4*)(in + i);
  const float4 b = *(const float4*)(in + i + 4);
  unsigned int r[4];
  r[0] = pack2bf(a.x, a.y);
  r[1] = pack2bf(a.z, a.w);
  r[2] = pack2bf(b.x, b.y);
  r[3] = pack2bf(b.z, b.w);
  *(uint4*)(out + i) = *(const uint4*)r;
}

// ------- f32 transpose + bf16 convert: in [R][C] f32 -> out [C][R] bf16 ----
// 64x64 tile as a pure u32-word transpose; LDS stride 69 (==5 mod 32):
// both sides 2-way-max bank access (free).
__global__ __launch_bounds__(256)
void transpose_cvt_kernel(const float* __restrict__ in,
                          __hip_bfloat16* __restrict__ out, int R, int C) {
  __shared__ unsigned int wbuf[32 * 69];
  const long long base = (long long)blockIdx.z * R * C;
  const int c0 = blockIdx.x * 64;
  const int r0 = blockIdx.y * 64;
  const int t = threadIdx.x;
  {
    const int p = t >> 3, g = t & 7;      // row-pair p, 8-col group g
    const float* s0 = in + base + (long long)(r0 + 2 * p) * C + c0 + g * 8;
    const float4 a0 = *(const float4*)(s0);
    const float4 a1 = *(const float4*)(s0 + 4);
    const float4 b0 = *(const float4*)(s0 + C);
    const float4 b1v = *(const float4*)(s0 + C + 4);
    unsigned int* dp = &wbuf[p * 69 + g * 8];
    dp[0] = pack2bf(a0.x, b0.x);
    dp[1] = pack2bf(a0.y, b0.y);
    dp[2] = pack2bf(a0.z, b0.z);
    dp[3] = pack2bf(a0.w, b0.w);
    dp[4] = pack2bf(a1.x, b1v.x);
    dp[5] = pack2bf(a1.y, b1v.y);
    dp[6] = pack2bf(a1.z, b1v.z);
    dp[7] = pack2bf(a1.w, b1v.w);
  }
  __syncthreads();
  {
    const int oc = t >> 2, rq = t & 3;    // out row c0+oc, word group rq
    __align__(16) unsigned int res[8];
#pragma unroll
    for (int j = 0; j < 8; ++j) res[j] = wbuf[(rq * 8 + j) * 69 + oc];
    __hip_bfloat16* dstp = out + base + (long long)(c0 + oc) * R + r0 + rq * 16;
    *(uint4*)dstp = *(const uint4*)&res[0];
    *(uint4*)(dstp + 8) = *(const uint4*)&res[4];
  }
}

// ---------------- grouped NT GEMM, depth-3 asm-pipelined ----------------
// C[m][n] = sum_k A[m][k]*BT[n][k]; 128x128 tile, BK=32.
// LDS: 4 buffers x (A 8KB | B 8KB) = 64KB -> 2 blocks/CU (TLP) AND depth-3
// prefetch with counted asm vmcnt(8/4/0) + raw s_barrier (1 per iter).
// Fragment reads are INLINE-ASM ds_read_b128 (+ manual lgkmcnt(0) +
// sched_barrier(0), rule-18) so the compiler cannot insert a vmcnt(0) drain
// against the in-flight global_load_lds prefetches.
// LDS swizzle (per 64B row of 4 16B slots): slot = kc ^ q(row),
// q(row)=(row&3)^((row>>2)&3). Applied to BOTH the pre-permuted global source
// (dest linear) and the ds_read address; every consecutive-8-lane phase of a
// ds_read_b128 sweeps all 8 bank-groups -> conflict-free.
// MODE 0: A = y_bf16 (rows via perm), epilogue tanh(x+b1) -> hid bf16 (permuted)
// MODE 1: A = hid (contiguous rows), epilogue full output -> f32 out[perm[i]]
template <int MODE>
__global__ __launch_bounds__(256, 2)
void gemm_kernel(const __hip_bfloat16* __restrict__ A,
                 const __hip_bfloat16* __restrict__ BT,   // [E][N][K] bf16
                 const float* __restrict__ bias,          // [E][N] f32
                 const int* __restrict__ offs, const int* __restrict__ perm,
                 const int* __restrict__ wl,              // work-list [64]
                 void* __restrict__ dstv,                 // MODE0: bf16*, MODE1: f32*
                 const float* __restrict__ yin,           // [B][N] f32 (MODE 1)
                 const float* __restrict__ scales,        // [N] f32 (MODE 1)
                 const float* __restrict__ shifta,
                 const float* __restrict__ shiftb,
                 int K, int N) {
  const int wle = wl[blockIdx.y];
  if (wle < 0) return;
  const int e  = wle & 15;
  const int mt = wle >> 4;
  const int off = offs[e];
  const int cnt = offs[e + 1] - off;
  const int m0 = mt * 128;
  if (m0 >= cnt) return;
  const int rows = min(128, cnt - m0);
  const int n0 = blockIdx.x * 128;

  __shared__ __align__(16) char lds[65536];   // 4 x (A 8K | B 8K)
  __shared__ int rowmap[128];

  const int tid = threadIdx.x;
  if (tid < 128) {
    int r = tid < rows ? tid : rows - 1;      // clamp: stage valid memory
    rowmap[tid] = (MODE == 0) ? perm[off + m0 + r] : (off + m0 + r);
  }
  __syncthreads();

  const int w = tid >> 6, l = tid & 63;

  // ---- staging: linear chunk c = i*256+tid at byte 16c; row=c>>2, s=c&3,
  // data kc = s ^ q(row); q(row) is per-thread constant across i.
  const int q_s = ((tid >> 2) & 3) ^ ((tid >> 4) & 3);
  const int kc  = (tid & 3) ^ q_s;
  const int r2  = tid >> 2;                   // row within 64-row i-block
  const __hip_bfloat16* aptr[2];
  const __hip_bfloat16* bptr[2];
#pragma unroll
  for (int i = 0; i < 2; ++i) {
    const int row = i * 64 + r2;
    aptr[i] = A + (long long)rowmap[row] * K + kc * 8;
    bptr[i] = BT + ((long long)e * N + n0 + row) * K + kc * 8;
  }

  auto stage = [&](int buf) {                 // 4 VMEM ops per wave
    char* dst = lds + (buf << 14);
#pragma unroll
    for (int i = 0; i < 2; ++i) {
      async_copy16(aptr[i], dst + i * 4096 + w * 1024);
      async_copy16(bptr[i], dst + 8192 + i * 4096 + w * 1024);
      aptr[i] += 32; bptr[i] += 32;
    }
  };

  floatx4 acc[4][4];
#pragma unroll
  for (int i = 0; i < 4; ++i)
#pragma unroll
    for (int j = 0; j < 4; ++j) acc[i][j] = (floatx4){0.f, 0.f, 0.f, 0.f};

  const int wm = w >> 1, wn = w & 1;
  const int fr = l & 15;                      // M (A) / N (B) index in fragment
  const int fq = l >> 4;                      // 16B K-chunk in fragment
  const int slot = fq ^ ((fr & 3) ^ ((fr >> 2) & 3));
  const unsigned lbase = (unsigned)(unsigned long long)
      (__attribute__((address_space(3))) char*)lds;
  const unsigned abase = lbase + (unsigned)((wm * 64 + fr) * 64 + slot * 16);
  const unsigned bbase = lbase + 8192u + (unsigned)((wn * 64 + fr) * 64 + slot * 16);

  auto compute = [&](int buf) {
    const unsigned ab = abase + (unsigned)(buf << 14);
    const unsigned bb = bbase + (unsigned)(buf << 14);
    short8 af0, af1, af2, af3, bf0, bf1, bf2, bf3;
    asm volatile("ds_read_b128 %0, %1" : "=v"(af0) : "v"(ab));
    asm volatile("ds_read_b128 %0, %1 offset:1024" : "=v"(af1) : "v"(ab));
    asm volatile("ds_read_b128 %0, %1 offset:2048" : "=v"(af2) : "v"(ab));
    asm volatile("ds_read_b128 %0, %1 offset:3072" : "=v"(af3) : "v"(ab));
    asm volatile("ds_read_b128 %0, %1" : "=v"(bf0) : "v"(bb));
    asm volatile("ds_read_b128 %0, %1 offset:1024" : "=v"(bf1) : "v"(bb));
    asm volatile("ds_read_b128 %0, %1 offset:2048" : "=v"(bf2) : "v"(bb));
    asm volatile("ds_read_b128 %0, %1 offset:3072" : "=v"(bf3) : "v"(bb));
    asm volatile("s_waitcnt lgkmcnt(0)" ::: "memory");
    __builtin_amdgcn_sched_barrier(0);
    short8 af[4] = {af0, af1, af2, af3};
    short8 bf[4] = {bf0, bf1, bf2, bf3};
#pragma unroll
    for (int mi = 0; mi < 4; ++mi)
#pragma unroll
      for (int ni = 0; ni < 4; ++ni)
        acc[mi][ni] = __builtin_amdgcn_mfma_f32_16x16x32_bf16(
            af[mi], bf[ni], acc[mi][ni], 0, 0, 0);
  };

  const int nt = K >> 5;                      // K-tiles of 32 (nt >= 4 here)

  stage(0); stage(1); stage(2);               // 12 outstanding per wave

  int t = 0;
  for (; t < nt - 3; ++t) {                   // steady state: depth-3
    asm volatile("s_waitcnt vmcnt(8)" ::: "memory");   // own stage(t) landed
    __builtin_amdgcn_s_barrier();             // whole tile t in LDS
    stage((t + 3) & 3);                       // buffer freed at barrier(t-1)
    compute(t & 3);
  }
  asm volatile("s_waitcnt vmcnt(8)" ::: "memory");
  __builtin_amdgcn_s_barrier();
  compute(t & 3); ++t;                        // t = nt-3
  asm volatile("s_waitcnt vmcnt(4)" ::: "memory");
  __builtin_amdgcn_s_barrier();
  compute(t & 3); ++t;                        // t = nt-2
  asm volatile("s_waitcnt vmcnt(0)" ::: "memory");
  __builtin_amdgcn_s_barrier();
  compute(t & 3);                             // t = nt-1

  float av = 0.f, bv = 0.f;
  if (MODE == 1) {
    const float sa = 1.f / (1.f + expf(-shifta[0]));
    const float sb = 1.f / (1.f + expf(-shiftb[0]));
    av = 0.0f + sa * (-1.0f - 0.0f);           // EIGINIT + sig*(EIGMIN-EIGINIT)
    bv = 0.0f + sb * (1.0f - 0.0f);            // EIGINIT + sig*(EIGMAX-EIGINIT)
  }

  // C/D layout: col = lane&15, row = (lane>>4)*4 + reg
#pragma unroll
  for (int mi = 0; mi < 4; ++mi) {
#pragma unroll
    for (int r = 0; r < 4; ++r) {
      const int rl = wm * 64 + mi * 16 + fq * 4 + r;
      if (rl >= rows) continue;
      const int i = off + m0 + rl;
      const int orig = (MODE == 1) ? perm[i] : 0;
#pragma unroll
      for (int ni = 0; ni < 4; ++ni) {
        const int cg = n0 + wn * 64 + ni * 16 + fr;
        const float x = acc[mi][ni][r] + bias[e * N + cg];
        if (MODE == 0) {
          ((__hip_bfloat16*)dstv)[(long long)i * N + cg] = __float2bfloat16(tanhf(x));
        } else {
          const float sc = 1.f / (1.f + expf(-scales[cg]));
          const float yv = yin[(long long)orig * N + cg];
          const float res = 0.5f * ((bv - av) * sc * x + (av + bv) * yv);
          ((float*)dstv)[(long long)orig * N + cg] = res;   // f32 output!
        }
      }
    }
  }
}

extern "C" void kernel_launch(void* const* d_in, const int* in_sizes, int n_in,
                              void* d_out, int out_size, void* d_ws, size_t ws_size,
                              hipStream_t stream) {
  const float* t      = (const float*)d_in[0];
  const float* y      = (const float*)d_in[1];
  const float* W1     = (const float*)d_in[2];
  const float* b1     = (const float*)d_in[3];
  const float* W2     = (const float*)d_in[4];
  const float* b2     = (const float*)d_in[5];
  const float* scales = (const float*)d_in[6];
  const float* shifta = (const float*)d_in[7];
  const float* shiftb = (const float*)d_in[8];

  // ws layout: [0,64MB)   transposed bf16 weights (W1T, then reused for W2T)
  //            [64,96MB)  hid bf16 [NB][DIM_H], permuted row order
  //            [96,104MB) y_bf16 [NB][DIM_D]
  //            [104MB,..) offs[16] + perm[NB] + wl[64]
  char* ws = (char*)d_ws;
  __hip_bfloat16* WT  = (__hip_bfloat16*)ws;
  __hip_bfloat16* hid = (__hip_bfloat16*)(ws + (size_t)64 * 1024 * 1024);
  __hip_bfloat16* ybf = (__hip_bfloat16*)(ws + (size_t)96 * 1024 * 1024);
  int* offs = (int*)(ws + (size_t)104 * 1024 * 1024);
  int* perm = offs + 16;
  int* wl   = perm + NB;

  setup_kernel<<<1, 256, 0, stream>>>(t, offs, perm, wl);

  cvt_kernel<<<(NB * DIM_D) / (256 * 8), 256, 0, stream>>>(y, ybf);

  // W1 [E][D][DH] f32 -> WT [E][DH][D] bf16
  transpose_cvt_kernel<<<dim3(DIM_H / 64, DIM_D / 64, NEXP), 256, 0, stream>>>(
      W1, WT, DIM_D, DIM_H);
  // hid = tanh(y @ W1 + b1), grouped by expert
  gemm_kernel<0><<<dim3(DIM_H / 128, 64), 256, 0, stream>>>(
      ybf, WT, b1, offs, perm, wl, hid, nullptr, nullptr, nullptr, nullptr,
      DIM_D, DIM_H);
  // W2 [E][DH][D] f32 -> WT [E][D][DH] bf16 (safe reuse: stream-ordered)
  transpose_cvt_kernel<<<dim3(DIM_D / 64, DIM_H / 64, NEXP), 256, 0, stream>>>(
      W2, WT, DIM_H, DIM_D);
  // out = 0.5*((b-a)*sig(scales)*(hid@W2+b2) + (a+b)*y), scattered via perm
  gemm_kernel<1><<<dim3(DIM_D / 128, 64), 256, 0, stream>>>(
      hid, WT, b2, offs, perm, wl, d_out, y, scales, shifta, shiftb,
      DIM_H, DIM_D);
}